// Round 21
// baseline (121.943 us; speedup 1.0000x reference)
//
#include <hip/hip_runtime.h>
#include <cstddef>

// ---------------------------------------------------------------------------
// MultiHead attention, B=4 T=1024 D=1024 N=16 DH=64, SCALE=32, causal + bias.
// Round 21: proj BK 64->32 (LDS 64->34.8KB => 3 blocks/CU co-resident, no
// serial occupancy tail; 64B rows, (row&3)<<4 swizzle; vmcnt(4) steady;
// same split-barrier counted-vmcnt schedule). gemm_out/attn/cvt = R20.
// ---------------------------------------------------------------------------

typedef __attribute__((ext_vector_type(8))) short bf16x8;
typedef __attribute__((ext_vector_type(4))) float f32x4;

#define MFMA16(a, b, c) __builtin_amdgcn_mfma_f32_16x16x32_bf16(a, b, c, 0, 0, 0)

__device__ __forceinline__ short f2bf(float f) {
  union { float f; unsigned int i; } v; v.f = f;
  unsigned int r = v.i + 0x7FFFu + ((v.i >> 16) & 1u);  // RNE
  return (short)(r >> 16);
}

__device__ __forceinline__ float fast_exp2(float x) {
  float r;
  asm volatile("v_exp_f32 %0, %1" : "=v"(r) : "v"(x));
  return r;
}

__device__ __forceinline__ unsigned int cvt_pk_bf16(float lo, float hi) {
  unsigned int r;
  asm volatile("v_cvt_pk_bf16_f32 %0, %1, %2" : "=v"(r) : "v"(lo), "v"(hi));
  return r;
}

__device__ __forceinline__ void gload_lds16(const void* g, void* l) {
  __builtin_amdgcn_global_load_lds(
      (const __attribute__((address_space(1))) void*)g,
      (__attribute__((address_space(3))) void*)l, 16, 0, 0);
}

// ---------------------------------------------------------------------------
// Fused f32 -> bf16 conversion for all 7 tensors (one launch).
// ---------------------------------------------------------------------------
__global__ __launch_bounds__(256) void cvt_all(
    const float* __restrict__ q, const float* __restrict__ k, const float* __restrict__ v,
    const float* __restrict__ wq, const float* __restrict__ wk,
    const float* __restrict__ wv, const float* __restrict__ wo,
    short* __restrict__ qb, short* __restrict__ kb, short* __restrict__ vb,
    short* __restrict__ wqb, short* __restrict__ wkb,
    short* __restrict__ wvb, short* __restrict__ wob) {
  const int total = 16 * 1048576 / 4;  // vec4 count
  int stride = gridDim.x * blockDim.x;
  for (int i = blockIdx.x * blockDim.x + threadIdx.x; i < total; i += stride) {
    int e = i * 4;
    int chunk = e >> 20;
    const float* s;
    short* d;
    int off;
    if (chunk < 12) {
      if (chunk < 4)      { s = q; d = qb; }
      else if (chunk < 8) { s = k; d = kb; }
      else                { s = v; d = vb; }
      off = e & (4 * 1048576 - 1);
    } else {
      int w = chunk - 12;
      if (w == 0)      { s = wq; d = wqb; }
      else if (w == 1) { s = wk; d = wkb; }
      else if (w == 2) { s = wv; d = wvb; }
      else             { s = wo; d = wob; }
      off = e & (1048576 - 1);
    }
    float4 x = *(const float4*)(s + off);
    short4 o;
    o.x = f2bf(x.x); o.y = f2bf(x.y); o.z = f2bf(x.z); o.w = f2bf(x.w);
    *(short4*)(d + off) = o;
  }
}

// ---------------------------------------------------------------------------
// Fused Q/K/V projection: 128x128 tile, 4 waves (2x2), BK=32, dbuf 32KB
// (34.8KB with epilogue repack => 3-4 blocks/CU), split-barrier counted-vmcnt
// (vmcnt(4) steady, never 0 mid-loop). 64B LDS rows, ^((r&3)<<4) swizzle.
// All outputs through LDS repack -> coalesced bf16x8 stores.
// ---------------------------------------------------------------------------
__global__ __launch_bounds__(256) void proj_qkv(
    const short* __restrict__ qA, const short* __restrict__ kA, const short* __restrict__ vA,
    const short* __restrict__ Wqb, const short* __restrict__ Wkb, const short* __restrict__ Wvb,
    const float* __restrict__ bq, const float* __restrict__ bk, const float* __restrict__ bv,
    short* __restrict__ Qh, short* __restrict__ Kh, short* __restrict__ Vth) {
  __shared__ short SMEM[17408];  // 2 x (A 4096 + B 4096) shorts = 32KB; Tt 34.8KB

  const int m0 = blockIdx.x * 128;
  const int n0 = blockIdx.y * 128;
  const int z = blockIdx.z;

  const short *A, *W;
  const float* bias;
  if (z == 0)      { A = qA; W = Wqb; bias = bq; }
  else if (z == 1) { A = kA; W = Wkb; bias = bk; }
  else             { A = vA; W = Wvb; bias = bv; }

  const int tid = threadIdx.x;
  const int wid = tid >> 6, lane = tid & 63;
  const int wr = wid >> 1, wc = wid & 1;
  const int fr = lane & 15, fq = lane >> 4;

  // stage one BK=32 tile pair into buffer buf: 4 gload_lds16 per wave.
  // Tiles are [128 rows][32 bf16] = 64B rows; logical col ^= ((row&3)<<4).
  auto stage = [&](int buf, int kt) {
    char* dA = (char*)(SMEM + buf * 8192);
    char* dB = dA + 8192;
#pragma unroll
    for (int c = 0; c < 2; ++c) {
      int pbase = c * 4096 + wid * 1024;
      int pb = pbase + lane * 16;
      int row = pb >> 6;
      int gcol = ((pb & 63) ^ ((row & 3) << 4)) >> 1;
      gload_lds16(A + (size_t)(m0 + row) * 1024 + kt * 32 + gcol, dA + pbase);
      gload_lds16(W + (size_t)(n0 + row) * 1024 + kt * 32 + gcol, dB + pbase);
    }
  };

  f32x4 acc[4][4] = {};
  // prologue: stage tiles 0,1; wait tile 0 only (tile 1's 4 stay in flight)
  stage(0, 0);
  stage(1, 1);
  asm volatile("s_waitcnt vmcnt(4)" ::: "memory");
  __builtin_amdgcn_sched_barrier(0);
  __builtin_amdgcn_s_barrier();
  __builtin_amdgcn_sched_barrier(0);

  for (int kt = 0; kt < 32; ++kt) {
    const char* As = (const char*)(SMEM + (kt & 1) * 8192);
    const char* Bs = As + 8192;
    bf16x8 af[4], bg[4];
#pragma unroll
    for (int m = 0; m < 4; ++m) {
      int r = wr * 64 + m * 16 + fr;
      af[m] = *(const bf16x8*)(As + ((r << 6) + (fq * 16 ^ ((r & 3) << 4))));
    }
#pragma unroll
    for (int n = 0; n < 4; ++n) {
      int r = wc * 64 + n * 16 + fr;
      bg[n] = *(const bf16x8*)(Bs + ((r << 6) + (fq * 16 ^ ((r & 3) << 4))));
    }
#pragma unroll
    for (int m = 0; m < 4; ++m)
#pragma unroll
      for (int n = 0; n < 4; ++n)
        acc[m][n] = MFMA16(af[m], bg[n], acc[m][n]);

    // -------- split-barrier counted-vmcnt tail --------
    if (kt + 2 < 32) {
      __builtin_amdgcn_sched_barrier(0);
      __builtin_amdgcn_s_barrier();       // (1) all waves done reading buf
      __builtin_amdgcn_sched_barrier(0);
      stage(kt & 1, kt + 2);              // overwrite just-freed buffer
    }
    if (kt + 1 < 32) {
      if (kt + 2 < 32) asm volatile("s_waitcnt vmcnt(4)" ::: "memory");
      else             asm volatile("s_waitcnt vmcnt(0)" ::: "memory");
      __builtin_amdgcn_sched_barrier(0);
      __builtin_amdgcn_s_barrier();       // (2) tile kt+1 landed for ALL waves
      __builtin_amdgcn_sched_barrier(0);
    }
  }
  // all waves done with last compute before epilogue overwrites SMEM
  __builtin_amdgcn_sched_barrier(0);
  __builtin_amdgcn_s_barrier();
  __builtin_amdgcn_sched_barrier(0);

  const int bb = m0 >> 10, t0 = m0 & 1023;
  if (z < 2) {
    // re-layout through LDS: [row_local][col_local], stride 136
    short* Tt = SMEM;
    short* dst = (z == 0) ? Qh : Kh;
#pragma unroll
    for (int m = 0; m < 4; ++m)
#pragma unroll
      for (int n = 0; n < 4; ++n) {
        int coll = wc * 64 + n * 16 + fr;
        float bval = bias[n0 + coll];
        int rowl0 = wr * 64 + m * 16 + fq * 4;
#pragma unroll
        for (int j = 0; j < 4; ++j)
          Tt[(rowl0 + j) * 136 + coll] = f2bf(acc[m][n][j] + bval);
      }
    __syncthreads();
#pragma unroll
    for (int it = 0; it < 8; ++it) {
      int qq = tid + it * 256;          // 2048 chunks: 128 rows x 16 chunks
      int rowl = qq >> 4, seg = qq & 15;
      bf16x8 vv = *(const bf16x8*)&Tt[rowl * 136 + seg * 8];
      int col = n0 + seg * 8;
      int hh = col >> 6, dh = col & 63;
      *(bf16x8*)&dst[(((size_t)(bb * 16 + hh)) * 1024 + t0 + rowl) * 64 + dh] = vv;
    }
  } else {
    // transpose 128x128 block through LDS, then coalesced bf16x8 stores
    short* Vt = SMEM;
#pragma unroll
    for (int m = 0; m < 4; ++m)
#pragma unroll
      for (int n = 0; n < 4; ++n) {
        int coll = wc * 64 + n * 16 + fr;
        float bval = bias[n0 + coll];
        int rowl0 = wr * 64 + m * 16 + fq * 4;
#pragma unroll
        for (int j = 0; j < 4; ++j)
          Vt[coll * 136 + rowl0 + j] = f2bf(acc[m][n][j] + bval);
      }
    __syncthreads();
#pragma unroll
    for (int it = 0; it < 8; ++it) {
      int qq = tid + it * 256;
      int rowl = qq >> 4, seg = qq & 15;
      bf16x8 vv = *(const bf16x8*)&Vt[rowl * 136 + seg * 8];
      int cg = n0 + rowl, hh = cg >> 6, dh = cg & 63;
      *(bf16x8*)&Vth[(((size_t)(bb * 16 + hh)) * 64 + dh) * 1024 + t0 + seg * 8] = vv;
    }
  }
}

// ---------------------------------------------------------------------------
// Output projection: 512 thr / 8 waves (2x4), 128x128 tile, dbuf, split-
// barrier counted-vmcnt (vmcnt(4) steady). d_out f32 = A @ Wo^T + bo. (R20)
// ---------------------------------------------------------------------------
__global__ __launch_bounds__(512) void gemm_out(const short* __restrict__ A,
                                                const short* __restrict__ W,
                                                const float* __restrict__ bias,
                                                float* __restrict__ C) {
  __shared__ short DS[2][16384];

  const int m0 = blockIdx.x * 128;
  const int n0 = blockIdx.y * 128;

  const int tid = threadIdx.x;
  const int wid = tid >> 6, lane = tid & 63;
  const int wr = wid >> 2, wc = wid & 3;   // 2 x 4 wave grid; wave = 64x32
  const int fr = lane & 15, fq = lane >> 4;

  auto stage = [&](int buf, int kt) {  // 4 gload_lds16 per wave
#pragma unroll
    for (int c = 0; c < 2; ++c) {
      int pbase = c * 8192 + wid * 1024;
      int pb = pbase + lane * 16;
      int lb = pb ^ (((pb >> 7) & 7) << 4);
      int grow = lb >> 7, gcol = (lb & 127) >> 1;
      gload_lds16(A + (size_t)(m0 + grow) * 1024 + kt * 64 + gcol,
                  (char*)DS[buf] + pbase);
      gload_lds16(W + (size_t)(n0 + grow) * 1024 + kt * 64 + gcol,
                  (char*)(DS[buf] + 8192) + pbase);
    }
  };

  f32x4 acc[4][2] = {};
  stage(0, 0);
  stage(1, 1);
  asm volatile("s_waitcnt vmcnt(4)" ::: "memory");
  __builtin_amdgcn_sched_barrier(0);
  __builtin_amdgcn_s_barrier();
  __builtin_amdgcn_sched_barrier(0);

  for (int kt = 0; kt < 16; ++kt) {
    const short* As = DS[kt & 1];
    const short* Bs = DS[kt & 1] + 8192;
#pragma unroll
    for (int kk = 0; kk < 2; ++kk) {
      bf16x8 af[4], bg[2];
      int cb = (fq * 8 + kk * 32) * 2;
#pragma unroll
      for (int m = 0; m < 4; ++m) {
        int r = wr * 64 + m * 16 + fr;
        af[m] = *(const bf16x8*)((const char*)As + (((r << 7) + cb) ^ ((r & 7) << 4)));
      }
#pragma unroll
      for (int n = 0; n < 2; ++n) {
        int r = wc * 32 + n * 16 + fr;
        bg[n] = *(const bf16x8*)((const char*)Bs + (((r << 7) + cb) ^ ((r & 7) << 4)));
      }
#pragma unroll
      for (int m = 0; m < 4; ++m)
#pragma unroll
        for (int n = 0; n < 2; ++n)
          acc[m][n] = MFMA16(af[m], bg[n], acc[m][n]);
    }
    // -------- split-barrier counted-vmcnt tail --------
    if (kt + 2 < 16) {
      __builtin_amdgcn_sched_barrier(0);
      __builtin_amdgcn_s_barrier();
      __builtin_amdgcn_sched_barrier(0);
      stage(kt & 1, kt + 2);
    }
    if (kt + 1 < 16) {
      if (kt + 2 < 16) asm volatile("s_waitcnt vmcnt(4)" ::: "memory");
      else             asm volatile("s_waitcnt vmcnt(0)" ::: "memory");
      __builtin_amdgcn_sched_barrier(0);
      __builtin_amdgcn_s_barrier();
      __builtin_amdgcn_sched_barrier(0);
    }
  }

#pragma unroll
  for (int m = 0; m < 4; ++m)
#pragma unroll
    for (int n = 0; n < 2; ++n) {
      int col = n0 + wc * 32 + n * 16 + fr;
      float bval = bias[col];
      int row0 = m0 + wr * 64 + m * 16 + fq * 4;
#pragma unroll
      for (int j = 0; j < 4; ++j)
        C[(size_t)(row0 + j) * 1024 + col] = acc[m][n][j] + bval;
    }
}

// ---------------------------------------------------------------------------
// Flash attention (R16/R19, exact): grid (8 q-pairs, 64 heads), 4 waves,
// QBLK=64, KVBLK=64, balanced pairs {15-bx, bx}, split-barrier counted-vmcnt
// (vmcnt(8) steady, never 0 mid-loop).
// ---------------------------------------------------------------------------
__global__ __launch_bounds__(256) void attn_kernel(
    const short* __restrict__ Qh, const short* __restrict__ Kh,
    const short* __restrict__ Vth, const float* __restrict__ Wb,
    const float* __restrict__ mask, short* __restrict__ Aout) {
  __shared__ short Ks[2][4096];        // [k][dh] bf16, 128B rows, ^((r&7)<<4)
  __shared__ short Vs[2][4096];        // [dh][k] bf16, 128B rows, ^((r&7)<<4)
  __shared__ float Bi[2][4096];        // [q][k] f32, 256B rows, ^(((pb>>8)&7)<<4)
  __shared__ unsigned short Mp[1024];  // bf16 mask penalties (staged once)
  __shared__ short Ps[4][16 * 72];     // per-wave P [16 q][64 k], stride 72

  const int tid = threadIdx.x;
  const int wid = tid >> 6, lane = tid & 63;
  const int fr = lane & 15, fq = lane >> 4;
  const int h = blockIdx.y, b = h >> 4;
  const int bx = blockIdx.x;

  const float C2 = 0.045084439f;      // log2(e)/32
  const float PEN2 = 4.5084440e8f;    // 3.125e8 * log2(e)

  const short* Kbase = Kh + (size_t)h * 1024 * 64;
  const short* Vbase = Vth + (size_t)h * 64 * 1024;
  const float* wbase = Wb + (size_t)h * 1024 * 1024;

  auto stage = [&](int buf, int kt2, int q0) {  // 8 gload_lds16 per wave
    const int k0 = kt2 * 64;
#pragma unroll
    for (int c = 0; c < 2; ++c) {  // K tile 8KB + V^T tile 8KB (128B rows)
      int pbase = c * 4096 + wid * 1024;
      int pb = pbase + lane * 16;
      int lb = pb ^ (((pb >> 7) & 7) << 4);
      int grow = lb >> 7, gcol = (lb & 127) >> 1;
      gload_lds16(Kbase + (size_t)(k0 + grow) * 64 + gcol, (char*)Ks[buf] + pbase);
      gload_lds16(Vbase + (size_t)grow * 1024 + k0 + gcol, (char*)Vs[buf] + pbase);
    }
#pragma unroll
    for (int c = 0; c < 4; ++c) {  // bias tile 16KB: rows q, 256B (64 f32)
      int pbase = c * 4096 + wid * 1024;
      int pb = pbase + lane * 16;
      int lb = pb ^ (((pb >> 8) & 7) << 4);
      int grow = lb >> 8, gcolf = (lb & 255) >> 2;
      gload_lds16(wbase + (size_t)(q0 + grow) * 1024 + k0 + gcolf,
                  (char*)Bi[buf] + pbase);
    }
  };

  // mask penalties -> LDS (bf16), once per block
  {
    float4 mv = *(const float4*)(mask + b * 1024 + tid * 4);
    ushort4 mp;
    mp.x = (unsigned short)f2bf((1.0f - mv.x) * PEN2);
    mp.y = (unsigned short)f2bf((1.0f - mv.y) * PEN2);
    mp.z = (unsigned short)f2bf((1.0f - mv.z) * PEN2);
    mp.w = (unsigned short)f2bf((1.0f - mv.w) * PEN2);
    *(ushort4*)&Mp[tid * 4] = mp;
  }

  for (int half = 0; half < 2; ++half) {
    const int qi = half ? bx : 15 - bx;
    const int q0 = qi * 64;
    const int qrow = q0 + wid * 16 + fr;   // this lane's q-row
    const int NT = qi + 1;                 // 64-wide KV tiles (NT >= 1)

    const short* qbase = Qh + ((size_t)h * 1024 + qrow) * 64 + fq * 8;
    bf16x8 qf0 = *(const bf16x8*)qbase;
    bf16x8 qf1 = *(const bf16x8*)(qbase + 32);

    if (half) {
      __builtin_amdgcn_sched_barrier(0);
      __builtin_amdgcn_s_barrier();
      __builtin_amdgcn_sched_barrier(0);
    }
    stage(0, 0, q0);
    if (NT > 1) stage(1, 1, q0);
    if (NT > 1) asm volatile("s_waitcnt vmcnt(8) lgkmcnt(0)" ::: "memory");
    else        asm volatile("s_waitcnt vmcnt(0) lgkmcnt(0)" ::: "memory");
    __builtin_amdgcn_sched_barrier(0);
    __builtin_amdgcn_s_barrier();
    __builtin_amdgcn_sched_barrier(0);

    f32x4 o_acc[4] = {};
    float m_run = -3.0e38f, l_run = 0.f;
    int cur = 0;

    for (int kt = 0; kt < NT; ++kt) {
      const int k0 = kt * 64;
      const bool diag = (kt == NT - 1);

      // S^T = K·Q^T
      f32x4 s_acc[4] = {};
      __builtin_amdgcn_s_setprio(1);
#pragma unroll
      for (int kk = 0; kk < 2; ++kk)
#pragma unroll
        for (int nt = 0; nt < 4; ++nt) {
          int r = nt * 16 + fr;
          int cb = fq * 16 + kk * 64;
          bf16x8 kf = *(const bf16x8*)((const char*)Ks[cur] + (((r << 7) + cb) ^ ((r & 7) << 4)));
          s_acc[nt] = MFMA16(kf, kk == 0 ? qf0 : qf1, s_acc[nt]);
        }
      __builtin_amdgcn_s_setprio(0);

      // bias from LDS
      f32x4 bv[4];
#pragma unroll
      for (int nt = 0; nt < 4; ++nt) {
        int lbyte = (wid * 16 + fr) * 256 + nt * 64 + fq * 16;
        bv[nt] = *(const f32x4*)((const char*)Bi[cur] + (lbyte ^ ((fr & 7) << 4)));
      }
      // mask penalties from LDS (bf16 -> f32)
      float pen[16];
#pragma unroll
      for (int nt = 0; nt < 4; ++nt) {
        ushort4 m4 = *(const ushort4*)&Mp[k0 + nt * 16 + fq * 4];
        pen[nt * 4 + 0] = __uint_as_float((unsigned)m4.x << 16);
        pen[nt * 4 + 1] = __uint_as_float((unsigned)m4.y << 16);
        pen[nt * 4 + 2] = __uint_as_float((unsigned)m4.z << 16);
        pen[nt * 4 + 3] = __uint_as_float((unsigned)m4.w << 16);
      }

      // logits in log2 domain
      float p[16];
#pragma unroll
      for (int nt = 0; nt < 4; ++nt)
#pragma unroll
        for (int j = 0; j < 4; ++j) {
          float s = (s_acc[nt][j] + bv[nt][j]) * C2 - pen[nt * 4 + j];
          if (diag && (nt * 16 + fq * 4 + j) > (wid * 16 + fr)) s = -3.0e38f;
          p[nt * 4 + j] = s;
        }

      // tree max over 16 + 2 shuffles -> row max
      float t8[8], t4m[4];
#pragma unroll
      for (int i = 0; i < 8; ++i) t8[i] = fmaxf(p[i], p[i + 8]);
#pragma unroll
      for (int i = 0; i < 4; ++i) t4m[i] = fmaxf(t8[i], t8[i + 4]);
      float pmax = fmaxf(fmaxf(t4m[0], t4m[1]), fmaxf(t4m[2], t4m[3]));
      pmax = fmaxf(pmax, __shfl_xor(pmax, 16));
      pmax = fmaxf(pmax, __shfl_xor(pmax, 32));

      // defer-max: rescale only when max grew past THR (11.5 log2 ~ 8 nats)
      if (!__all(pmax - m_run <= 11.5f)) {
        float mnew = fmaxf(m_run, pmax);
        float corr = fast_exp2(m_run - mnew);
        m_run = mnew;
        l_run *= corr;
#pragma unroll
        for (int nt = 0; nt < 4; ++nt) o_acc[nt] *= corr;
      }

#pragma unroll
      for (int i = 0; i < 16; ++i) p[i] = fast_exp2(p[i] - m_run);
      float a8[8], a4[4];
#pragma unroll
      for (int i = 0; i < 8; ++i) a8[i] = p[i] + p[i + 8];
#pragma unroll
      for (int i = 0; i < 4; ++i) a4[i] = a8[i] + a8[i + 4];
      float rsum = (a4[0] + a4[1]) + (a4[2] + a4[3]);
      rsum += __shfl_xor(rsum, 16);
      rsum += __shfl_xor(rsum, 32);
      l_run += rsum;

      // P[q=fr][k] -> per-wave LDS (cvt_pk, b64 writes)
#pragma unroll
      for (int nt = 0; nt < 4; ++nt) {
        uint2 w2;
        w2.x = cvt_pk_bf16(p[nt * 4 + 0], p[nt * 4 + 1]);
        w2.y = cvt_pk_bf16(p[nt * 4 + 2], p[nt * 4 + 3]);
        *(uint2*)&Ps[wid][fr * 72 + nt * 16 + fq * 4] = w2;
      }
      asm volatile("s_waitcnt lgkmcnt(0)" ::: "memory");
      __builtin_amdgcn_sched_barrier(0);
      bf16x8 pf0 = *(const bf16x8*)&Ps[wid][fr * 72 + fq * 8];
      bf16x8 pf1 = *(const bf16x8*)&Ps[wid][fr * 72 + fq * 8 + 32];

      // O += V^T · P
      __builtin_amdgcn_s_setprio(1);
#pragma unroll
      for (int kk = 0; kk < 2; ++kk)
#pragma unroll
        for (int nt = 0; nt < 4; ++nt) {
          int r = nt * 16 + fr;
          int cb = fq * 16 + kk * 64;
          bf16x8 vf = *(const bf16x8*)((const char*)Vs[cur] + (((r << 7) + cb) ^ ((r & 7) << 4)));
          o_acc[nt] = MFMA16(vf, kk == 0 ? pf0 : pf1, o_acc[nt]);
        }
      __builtin_amdgcn_s_setprio(0);

      // -------- split-barrier counted-vmcnt tail --------
      if (kt + 2 < NT) {
        __builtin_amdgcn_sched_barrier(0);
        __builtin_amdgcn_s_barrier();       // (1) all waves done with buf[cur]
        __builtin_amdgcn_sched_barrier(0);
        stage(cur, kt + 2, q0);             // overwrite just-freed buffer
      }
      if (kt + 1 < NT) {
        if (kt + 2 < NT) asm volatile("s_waitcnt vmcnt(8)" ::: "memory");
        else             asm volatile("s_waitcnt vmcnt(0)" ::: "memory");
        __builtin_amdgcn_sched_barrier(0);
        __builtin_amdgcn_s_barrier();       // (2) tile kt+1 landed
        __builtin_amdgcn_sched_barrier(0);
      }
      cur ^= 1;
    }

    // normalize + write merged-head bf16 [4096][1024] for this half
    float rl = 1.0f / l_run;
    size_t row = (size_t)(b * 1024 + q0 + wid * 16 + fr);
#pragma unroll
    for (int nt = 0; nt < 4; ++nt) {
      uint2 sv;
      sv.x = cvt_pk_bf16(o_acc[nt][0] * rl, o_acc[nt][1] * rl);
      sv.y = cvt_pk_bf16(o_acc[nt][2] * rl, o_acc[nt][3] * rl);
      int col = (h & 15) * 64 + nt * 16 + fq * 4;
      *(uint2*)&Aout[row * 1024 + col] = sv;
    }
  }
}

// ---------------------------------------------------------------------------
extern "C" void kernel_launch(void* const* d_in, const int* in_sizes, int n_in,
                              void* d_out, int out_size, void* d_ws, size_t ws_size,
                              hipStream_t stream) {
  const float* query = (const float*)d_in[0];
  const float* key   = (const float*)d_in[1];
  const float* value = (const float*)d_in[2];
  const float* mask  = (const float*)d_in[3];
  const float* wts   = (const float*)d_in[4];
  const float* Wq    = (const float*)d_in[5];
  const float* bq    = (const float*)d_in[6];
  const float* Wk    = (const float*)d_in[7];
  const float* bk    = (const float*)d_in[8];
  const float* Wv    = (const float*)d_in[9];
  const float* bv    = (const float*)d_in[10];
  const float* Wo    = (const float*)d_in[11];
  const float* bo    = (const float*)d_in[12];

  char* ws = (char*)d_ws;
  const size_t MB = 1u << 20;
  short* qbf = (short*)(ws + 0);        // 8 MB  (reused as attn out)
  short* kbf = (short*)(ws + 8 * MB);   // 8 MB
  short* vbf = (short*)(ws + 16 * MB);  // 8 MB
  short* Wqb = (short*)(ws + 24 * MB);  // 2 MB
  short* Wkb = (short*)(ws + 26 * MB);
  short* Wvb = (short*)(ws + 28 * MB);
  short* Wob = (short*)(ws + 30 * MB);
  short* Qh  = (short*)(ws + 32 * MB);  // 8 MB [B,N,T,DH]
  short* Kh  = (short*)(ws + 40 * MB);  // 8 MB [B,N,T,DH]
  short* Vth = (short*)(ws + 48 * MB);  // 8 MB [B,N,DH,T]
  short* attnb = qbf;                   // alias: qbf dead after proj_qkv

  cvt_all<<<dim3(2048), dim3(256), 0, stream>>>(query, key, value, Wq, Wk, Wv, Wo,
                                                qbf, kbf, vbf, Wqb, Wkb, Wvb, Wob);
  proj_qkv<<<dim3(32, 8, 3), dim3(256), 0, stream>>>(qbf, kbf, vbf, Wqb, Wkb, Wvb,
                                                     bq, bk, bv, Qh, Kh, Vth);
  attn_kernel<<<dim3(8, 64), dim3(256), 0, stream>>>(Qh, Kh, Vth, wts, mask, attnb);
  gemm_out<<<dim3(32, 8), dim3(512), 0, stream>>>(attnb, Wob, bo, (float*)d_out);
}

// Round 22
// 111.095 us; speedup vs baseline: 1.0977x; 1.0977x over previous
//
#include <hip/hip_runtime.h>
#include <cstddef>

// ---------------------------------------------------------------------------
// MultiHead attention, B=4 T=1024 D=1024 N=16 DH=64, SCALE=32, causal + bias.
// Round 22: REVERT to R20 (measured best, 111.4us). proj BK=64 dbuf with
// split-barrier counted-vmcnt; gemm_out 8-wave same schedule; attn R16
// balanced-pair KVBLK=64 counted-vmcnt; fused cvt. (R21's BK=32 doubled
// barrier count -> +10us; third confirmation that smaller K-tiles lose.)
// ---------------------------------------------------------------------------

typedef __attribute__((ext_vector_type(8))) short bf16x8;
typedef __attribute__((ext_vector_type(4))) float f32x4;

#define MFMA16(a, b, c) __builtin_amdgcn_mfma_f32_16x16x32_bf16(a, b, c, 0, 0, 0)

__device__ __forceinline__ short f2bf(float f) {
  union { float f; unsigned int i; } v; v.f = f;
  unsigned int r = v.i + 0x7FFFu + ((v.i >> 16) & 1u);  // RNE
  return (short)(r >> 16);
}

__device__ __forceinline__ float fast_exp2(float x) {
  float r;
  asm volatile("v_exp_f32 %0, %1" : "=v"(r) : "v"(x));
  return r;
}

__device__ __forceinline__ unsigned int cvt_pk_bf16(float lo, float hi) {
  unsigned int r;
  asm volatile("v_cvt_pk_bf16_f32 %0, %1, %2" : "=v"(r) : "v"(lo), "v"(hi));
  return r;
}

__device__ __forceinline__ void gload_lds16(const void* g, void* l) {
  __builtin_amdgcn_global_load_lds(
      (const __attribute__((address_space(1))) void*)g,
      (__attribute__((address_space(3))) void*)l, 16, 0, 0);
}

// ---------------------------------------------------------------------------
// Fused f32 -> bf16 conversion for all 7 tensors (one launch).
// ---------------------------------------------------------------------------
__global__ __launch_bounds__(256) void cvt_all(
    const float* __restrict__ q, const float* __restrict__ k, const float* __restrict__ v,
    const float* __restrict__ wq, const float* __restrict__ wk,
    const float* __restrict__ wv, const float* __restrict__ wo,
    short* __restrict__ qb, short* __restrict__ kb, short* __restrict__ vb,
    short* __restrict__ wqb, short* __restrict__ wkb,
    short* __restrict__ wvb, short* __restrict__ wob) {
  const int total = 16 * 1048576 / 4;  // vec4 count
  int stride = gridDim.x * blockDim.x;
  for (int i = blockIdx.x * blockDim.x + threadIdx.x; i < total; i += stride) {
    int e = i * 4;
    int chunk = e >> 20;
    const float* s;
    short* d;
    int off;
    if (chunk < 12) {
      if (chunk < 4)      { s = q; d = qb; }
      else if (chunk < 8) { s = k; d = kb; }
      else                { s = v; d = vb; }
      off = e & (4 * 1048576 - 1);
    } else {
      int w = chunk - 12;
      if (w == 0)      { s = wq; d = wqb; }
      else if (w == 1) { s = wk; d = wkb; }
      else if (w == 2) { s = wv; d = wvb; }
      else             { s = wo; d = wob; }
      off = e & (1048576 - 1);
    }
    float4 x = *(const float4*)(s + off);
    short4 o;
    o.x = f2bf(x.x); o.y = f2bf(x.y); o.z = f2bf(x.z); o.w = f2bf(x.w);
    *(short4*)(d + off) = o;
  }
}

// ---------------------------------------------------------------------------
// Fused Q/K/V projection: 128x128 tile, 4 waves (2x2), BK=64, dbuf 64KB,
// split-barrier counted-vmcnt pipeline (vmcnt(8) steady, never 0 mid-loop).
// All outputs through LDS repack -> coalesced bf16x8 stores.
// ---------------------------------------------------------------------------
__global__ __launch_bounds__(256) void proj_qkv(
    const short* __restrict__ qA, const short* __restrict__ kA, const short* __restrict__ vA,
    const short* __restrict__ Wqb, const short* __restrict__ Wkb, const short* __restrict__ Wvb,
    const float* __restrict__ bq, const float* __restrict__ bk, const float* __restrict__ bv,
    short* __restrict__ Qh, short* __restrict__ Kh, short* __restrict__ Vth) {
  __shared__ short DS[2][16384];  // per buf: As 8192 + Bs 8192 shorts = 32KB

  const int m0 = blockIdx.x * 128;
  const int n0 = blockIdx.y * 128;
  const int z = blockIdx.z;

  const short *A, *W;
  const float* bias;
  if (z == 0)      { A = qA; W = Wqb; bias = bq; }
  else if (z == 1) { A = kA; W = Wkb; bias = bk; }
  else             { A = vA; W = Wvb; bias = bv; }

  const int tid = threadIdx.x;
  const int wid = tid >> 6, lane = tid & 63;
  const int wr = wid >> 1, wc = wid & 1;
  const int fr = lane & 15, fq = lane >> 4;

  auto stage = [&](int buf, int kt) {  // 8 gload_lds16 per wave
#pragma unroll
    for (int c = 0; c < 4; ++c) {
      int pbase = c * 4096 + wid * 1024;
      int pb = pbase + lane * 16;
      int lb = pb ^ (((pb >> 7) & 7) << 4);
      int grow = lb >> 7, gcol = (lb & 127) >> 1;
      gload_lds16(A + (size_t)(m0 + grow) * 1024 + kt * 64 + gcol,
                  (char*)DS[buf] + pbase);
      gload_lds16(W + (size_t)(n0 + grow) * 1024 + kt * 64 + gcol,
                  (char*)(DS[buf] + 8192) + pbase);
    }
  };

  f32x4 acc[4][4] = {};
  // prologue: stage tiles 0 and 1; wait tile 0 only (tile 1's 8 stay in flight)
  stage(0, 0);
  stage(1, 1);
  asm volatile("s_waitcnt vmcnt(8)" ::: "memory");
  __builtin_amdgcn_sched_barrier(0);
  __builtin_amdgcn_s_barrier();
  __builtin_amdgcn_sched_barrier(0);

  for (int kt = 0; kt < 16; ++kt) {
    const short* As = DS[kt & 1];
    const short* Bs = DS[kt & 1] + 8192;
#pragma unroll
    for (int kk = 0; kk < 2; ++kk) {
      bf16x8 af[4], bg[4];
      int cb = (fq * 8 + kk * 32) * 2;
#pragma unroll
      for (int m = 0; m < 4; ++m) {
        int r = wr * 64 + m * 16 + fr;
        af[m] = *(const bf16x8*)((const char*)As + (((r << 7) + cb) ^ ((r & 7) << 4)));
      }
#pragma unroll
      for (int n = 0; n < 4; ++n) {
        int r = wc * 64 + n * 16 + fr;
        bg[n] = *(const bf16x8*)((const char*)Bs + (((r << 7) + cb) ^ ((r & 7) << 4)));
      }
#pragma unroll
      for (int m = 0; m < 4; ++m)
#pragma unroll
        for (int n = 0; n < 4; ++n)
          acc[m][n] = MFMA16(af[m], bg[n], acc[m][n]);
    }
    // -------- split-barrier counted-vmcnt tail --------
    if (kt + 2 < 16) {
      __builtin_amdgcn_sched_barrier(0);
      __builtin_amdgcn_s_barrier();       // (1) all waves done reading DS[kt&1]
      __builtin_amdgcn_sched_barrier(0);
      stage(kt & 1, kt + 2);              // overwrite just-freed buffer
    }
    if (kt + 1 < 16) {
      if (kt + 2 < 16) asm volatile("s_waitcnt vmcnt(8)" ::: "memory");
      else             asm volatile("s_waitcnt vmcnt(0)" ::: "memory");
      __builtin_amdgcn_sched_barrier(0);
      __builtin_amdgcn_s_barrier();       // (2) tile kt+1 landed for ALL waves
      __builtin_amdgcn_sched_barrier(0);
    }
  }
  // all waves done with last compute before epilogue overwrites DS
  __builtin_amdgcn_sched_barrier(0);
  __builtin_amdgcn_s_barrier();
  __builtin_amdgcn_sched_barrier(0);

  const int bb = m0 >> 10, t0 = m0 & 1023;
  if (z < 2) {
    // re-layout through LDS: [row_local][col_local], stride 136
    short* Tt = (short*)DS;
    short* dst = (z == 0) ? Qh : Kh;
#pragma unroll
    for (int m = 0; m < 4; ++m)
#pragma unroll
      for (int n = 0; n < 4; ++n) {
        int coll = wc * 64 + n * 16 + fr;
        float bval = bias[n0 + coll];
        int rowl0 = wr * 64 + m * 16 + fq * 4;
#pragma unroll
        for (int j = 0; j < 4; ++j)
          Tt[(rowl0 + j) * 136 + coll] = f2bf(acc[m][n][j] + bval);
      }
    __syncthreads();
#pragma unroll
    for (int it = 0; it < 8; ++it) {
      int qq = tid + it * 256;          // 2048 chunks: 128 rows x 16 chunks
      int rowl = qq >> 4, seg = qq & 15;
      bf16x8 vv = *(const bf16x8*)&Tt[rowl * 136 + seg * 8];
      int col = n0 + seg * 8;
      int hh = col >> 6, dh = col & 63;
      *(bf16x8*)&dst[(((size_t)(bb * 16 + hh)) * 1024 + t0 + rowl) * 64 + dh] = vv;
    }
  } else {
    // transpose 128x128 block through LDS, then coalesced bf16x8 stores
    short* Vt = (short*)DS;
#pragma unroll
    for (int m = 0; m < 4; ++m)
#pragma unroll
      for (int n = 0; n < 4; ++n) {
        int coll = wc * 64 + n * 16 + fr;
        float bval = bias[n0 + coll];
        int rowl0 = wr * 64 + m * 16 + fq * 4;
#pragma unroll
        for (int j = 0; j < 4; ++j)
          Vt[coll * 136 + rowl0 + j] = f2bf(acc[m][n][j] + bval);
      }
    __syncthreads();
#pragma unroll
    for (int it = 0; it < 8; ++it) {
      int qq = tid + it * 256;
      int rowl = qq >> 4, seg = qq & 15;
      bf16x8 vv = *(const bf16x8*)&Vt[rowl * 136 + seg * 8];
      int cg = n0 + rowl, hh = cg >> 6, dh = cg & 63;
      *(bf16x8*)&Vth[(((size_t)(bb * 16 + hh)) * 64 + dh) * 1024 + t0 + seg * 8] = vv;
    }
  }
}

// ---------------------------------------------------------------------------
// Output projection: 512 thr / 8 waves (2x4), 128x128 tile, dbuf, split-
// barrier counted-vmcnt (vmcnt(4) steady). d_out f32 = A @ Wo^T + bo.
// ---------------------------------------------------------------------------
__global__ __launch_bounds__(512) void gemm_out(const short* __restrict__ A,
                                                const short* __restrict__ W,
                                                const float* __restrict__ bias,
                                                float* __restrict__ C) {
  __shared__ short DS[2][16384];

  const int m0 = blockIdx.x * 128;
  const int n0 = blockIdx.y * 128;

  const int tid = threadIdx.x;
  const int wid = tid >> 6, lane = tid & 63;
  const int wr = wid >> 2, wc = wid & 3;   // 2 x 4 wave grid; wave = 64x32
  const int fr = lane & 15, fq = lane >> 4;

  auto stage = [&](int buf, int kt) {  // 4 gload_lds16 per wave
#pragma unroll
    for (int c = 0; c < 2; ++c) {
      int pbase = c * 8192 + wid * 1024;
      int pb = pbase + lane * 16;
      int lb = pb ^ (((pb >> 7) & 7) << 4);
      int grow = lb >> 7, gcol = (lb & 127) >> 1;
      gload_lds16(A + (size_t)(m0 + grow) * 1024 + kt * 64 + gcol,
                  (char*)DS[buf] + pbase);
      gload_lds16(W + (size_t)(n0 + grow) * 1024 + kt * 64 + gcol,
                  (char*)(DS[buf] + 8192) + pbase);
    }
  };

  f32x4 acc[4][2] = {};
  stage(0, 0);
  stage(1, 1);
  asm volatile("s_waitcnt vmcnt(4)" ::: "memory");
  __builtin_amdgcn_sched_barrier(0);
  __builtin_amdgcn_s_barrier();
  __builtin_amdgcn_sched_barrier(0);

  for (int kt = 0; kt < 16; ++kt) {
    const short* As = DS[kt & 1];
    const short* Bs = DS[kt & 1] + 8192;
#pragma unroll
    for (int kk = 0; kk < 2; ++kk) {
      bf16x8 af[4], bg[2];
      int cb = (fq * 8 + kk * 32) * 2;
#pragma unroll
      for (int m = 0; m < 4; ++m) {
        int r = wr * 64 + m * 16 + fr;
        af[m] = *(const bf16x8*)((const char*)As + (((r << 7) + cb) ^ ((r & 7) << 4)));
      }
#pragma unroll
      for (int n = 0; n < 2; ++n) {
        int r = wc * 32 + n * 16 + fr;
        bg[n] = *(const bf16x8*)((const char*)Bs + (((r << 7) + cb) ^ ((r & 7) << 4)));
      }
#pragma unroll
      for (int m = 0; m < 4; ++m)
#pragma unroll
        for (int n = 0; n < 2; ++n)
          acc[m][n] = MFMA16(af[m], bg[n], acc[m][n]);
    }
    // -------- split-barrier counted-vmcnt tail --------
    if (kt + 2 < 16) {
      __builtin_amdgcn_sched_barrier(0);
      __builtin_amdgcn_s_barrier();
      __builtin_amdgcn_sched_barrier(0);
      stage(kt & 1, kt + 2);
    }
    if (kt + 1 < 16) {
      if (kt + 2 < 16) asm volatile("s_waitcnt vmcnt(4)" ::: "memory");
      else             asm volatile("s_waitcnt vmcnt(0)" ::: "memory");
      __builtin_amdgcn_sched_barrier(0);
      __builtin_amdgcn_s_barrier();
      __builtin_amdgcn_sched_barrier(0);
    }
  }

#pragma unroll
  for (int m = 0; m < 4; ++m)
#pragma unroll
    for (int n = 0; n < 2; ++n) {
      int col = n0 + wc * 32 + n * 16 + fr;
      float bval = bias[col];
      int row0 = m0 + wr * 64 + m * 16 + fq * 4;
#pragma unroll
      for (int j = 0; j < 4; ++j)
        C[(size_t)(row0 + j) * 1024 + col] = acc[m][n][j] + bval;
    }
}

// ---------------------------------------------------------------------------
// Flash attention (R16/R19, exact): grid (8 q-pairs, 64 heads), 4 waves,
// QBLK=64, KVBLK=64, balanced pairs {15-bx, bx}, split-barrier counted-vmcnt
// (vmcnt(8) steady, never 0 mid-loop).
// ---------------------------------------------------------------------------
__global__ __launch_bounds__(256) void attn_kernel(
    const short* __restrict__ Qh, const short* __restrict__ Kh,
    const short* __restrict__ Vth, const float* __restrict__ Wb,
    const float* __restrict__ mask, short* __restrict__ Aout) {
  __shared__ short Ks[2][4096];        // [k][dh] bf16, 128B rows, ^((r&7)<<4)
  __shared__ short Vs[2][4096];        // [dh][k] bf16, 128B rows, ^((r&7)<<4)
  __shared__ float Bi[2][4096];        // [q][k] f32, 256B rows, ^(((pb>>8)&7)<<4)
  __shared__ unsigned short Mp[1024];  // bf16 mask penalties (staged once)
  __shared__ short Ps[4][16 * 72];     // per-wave P [16 q][64 k], stride 72

  const int tid = threadIdx.x;
  const int wid = tid >> 6, lane = tid & 63;
  const int fr = lane & 15, fq = lane >> 4;
  const int h = blockIdx.y, b = h >> 4;
  const int bx = blockIdx.x;

  const float C2 = 0.045084439f;      // log2(e)/32
  const float PEN2 = 4.5084440e8f;    // 3.125e8 * log2(e)

  const short* Kbase = Kh + (size_t)h * 1024 * 64;
  const short* Vbase = Vth + (size_t)h * 64 * 1024;
  const float* wbase = Wb + (size_t)h * 1024 * 1024;

  auto stage = [&](int buf, int kt2, int q0) {  // 8 gload_lds16 per wave
    const int k0 = kt2 * 64;
#pragma unroll
    for (int c = 0; c < 2; ++c) {  // K tile 8KB + V^T tile 8KB (128B rows)
      int pbase = c * 4096 + wid * 1024;
      int pb = pbase + lane * 16;
      int lb = pb ^ (((pb >> 7) & 7) << 4);
      int grow = lb >> 7, gcol = (lb & 127) >> 1;
      gload_lds16(Kbase + (size_t)(k0 + grow) * 64 + gcol, (char*)Ks[buf] + pbase);
      gload_lds16(Vbase + (size_t)grow * 1024 + k0 + gcol, (char*)Vs[buf] + pbase);
    }
#pragma unroll
    for (int c = 0; c < 4; ++c) {  // bias tile 16KB: rows q, 256B (64 f32)
      int pbase = c * 4096 + wid * 1024;
      int pb = pbase + lane * 16;
      int lb = pb ^ (((pb >> 8) & 7) << 4);
      int grow = lb >> 8, gcolf = (lb & 255) >> 2;
      gload_lds16(wbase + (size_t)(q0 + grow) * 1024 + k0 + gcolf,
                  (char*)Bi[buf] + pbase);
    }
  };

  // mask penalties -> LDS (bf16), once per block
  {
    float4 mv = *(const float4*)(mask + b * 1024 + tid * 4);
    ushort4 mp;
    mp.x = (unsigned short)f2bf((1.0f - mv.x) * PEN2);
    mp.y = (unsigned short)f2bf((1.0f - mv.y) * PEN2);
    mp.z = (unsigned short)f2bf((1.0f - mv.z) * PEN2);
    mp.w = (unsigned short)f2bf((1.0f - mv.w) * PEN2);
    *(ushort4*)&Mp[tid * 4] = mp;
  }

  for (int half = 0; half < 2; ++half) {
    const int qi = half ? bx : 15 - bx;
    const int q0 = qi * 64;
    const int qrow = q0 + wid * 16 + fr;   // this lane's q-row
    const int NT = qi + 1;                 // 64-wide KV tiles (NT >= 1)

    const short* qbase = Qh + ((size_t)h * 1024 + qrow) * 64 + fq * 8;
    bf16x8 qf0 = *(const bf16x8*)qbase;
    bf16x8 qf1 = *(const bf16x8*)(qbase + 32);

    if (half) {
      __builtin_amdgcn_sched_barrier(0);
      __builtin_amdgcn_s_barrier();
      __builtin_amdgcn_sched_barrier(0);
    }
    stage(0, 0, q0);
    if (NT > 1) stage(1, 1, q0);
    if (NT > 1) asm volatile("s_waitcnt vmcnt(8) lgkmcnt(0)" ::: "memory");
    else        asm volatile("s_waitcnt vmcnt(0) lgkmcnt(0)" ::: "memory");
    __builtin_amdgcn_sched_barrier(0);
    __builtin_amdgcn_s_barrier();
    __builtin_amdgcn_sched_barrier(0);

    f32x4 o_acc[4] = {};
    float m_run = -3.0e38f, l_run = 0.f;
    int cur = 0;

    for (int kt = 0; kt < NT; ++kt) {
      const int k0 = kt * 64;
      const bool diag = (kt == NT - 1);

      // S^T = K·Q^T
      f32x4 s_acc[4] = {};
      __builtin_amdgcn_s_setprio(1);
#pragma unroll
      for (int kk = 0; kk < 2; ++kk)
#pragma unroll
        for (int nt = 0; nt < 4; ++nt) {
          int r = nt * 16 + fr;
          int cb = fq * 16 + kk * 64;
          bf16x8 kf = *(const bf16x8*)((const char*)Ks[cur] + (((r << 7) + cb) ^ ((r & 7) << 4)));
          s_acc[nt] = MFMA16(kf, kk == 0 ? qf0 : qf1, s_acc[nt]);
        }
      __builtin_amdgcn_s_setprio(0);

      // bias from LDS
      f32x4 bv[4];
#pragma unroll
      for (int nt = 0; nt < 4; ++nt) {
        int lbyte = (wid * 16 + fr) * 256 + nt * 64 + fq * 16;
        bv[nt] = *(const f32x4*)((const char*)Bi[cur] + (lbyte ^ ((fr & 7) << 4)));
      }
      // mask penalties from LDS (bf16 -> f32)
      float pen[16];
#pragma unroll
      for (int nt = 0; nt < 4; ++nt) {
        ushort4 m4 = *(const ushort4*)&Mp[k0 + nt * 16 + fq * 4];
        pen[nt * 4 + 0] = __uint_as_float((unsigned)m4.x << 16);
        pen[nt * 4 + 1] = __uint_as_float((unsigned)m4.y << 16);
        pen[nt * 4 + 2] = __uint_as_float((unsigned)m4.z << 16);
        pen[nt * 4 + 3] = __uint_as_float((unsigned)m4.w << 16);
      }

      // logits in log2 domain
      float p[16];
#pragma unroll
      for (int nt = 0; nt < 4; ++nt)
#pragma unroll
        for (int j = 0; j < 4; ++j) {
          float s = (s_acc[nt][j] + bv[nt][j]) * C2 - pen[nt * 4 + j];
          if (diag && (nt * 16 + fq * 4 + j) > (wid * 16 + fr)) s = -3.0e38f;
          p[nt * 4 + j] = s;
        }

      // tree max over 16 + 2 shuffles -> row max
      float t8[8], t4m[4];
#pragma unroll
      for (int i = 0; i < 8; ++i) t8[i] = fmaxf(p[i], p[i + 8]);
#pragma unroll
      for (int i = 0; i < 4; ++i) t4m[i] = fmaxf(t8[i], t8[i + 4]);
      float pmax = fmaxf(fmaxf(t4m[0], t4m[1]), fmaxf(t4m[2], t4m[3]));
      pmax = fmaxf(pmax, __shfl_xor(pmax, 16));
      pmax = fmaxf(pmax, __shfl_xor(pmax, 32));

      // defer-max: rescale only when max grew past THR (11.5 log2 ~ 8 nats)
      if (!__all(pmax - m_run <= 11.5f)) {
        float mnew = fmaxf(m_run, pmax);
        float corr = fast_exp2(m_run - mnew);
        m_run = mnew;
        l_run *= corr;
#pragma unroll
        for (int nt = 0; nt < 4; ++nt) o_acc[nt] *= corr;
      }

#pragma unroll
      for (int i = 0; i < 16; ++i) p[i] = fast_exp2(p[i] - m_run);
      float a8[8], a4[4];
#pragma unroll
      for (int i = 0; i < 8; ++i) a8[i] = p[i] + p[i + 8];
#pragma unroll
      for (int i = 0; i < 4; ++i) a4[i] = a8[i] + a8[i + 4];
      float rsum = (a4[0] + a4[1]) + (a4[2] + a4[3]);
      rsum += __shfl_xor(rsum, 16);
      rsum += __shfl_xor(rsum, 32);
      l_run += rsum;

      // P[q=fr][k] -> per-wave LDS (cvt_pk, b64 writes)
#pragma unroll
      for (int nt = 0; nt < 4; ++nt) {
        uint2 w2;
        w2.x = cvt_pk_bf16(p[nt * 4 + 0], p[nt * 4 + 1]);
        w2.y = cvt_pk_bf16(p[nt * 4 + 2], p[nt * 4 + 3]);
        *(uint2*)&Ps[wid][fr * 72 + nt * 16 + fq * 4] = w2;
      }
      asm volatile("s_waitcnt lgkmcnt(0)" ::: "memory");
      __builtin_amdgcn_sched_barrier(0);
      bf16x8 pf0 = *(const bf16x8*)&Ps[wid][fr * 72 + fq * 8];
      bf16x8 pf1 = *(const bf16x8*)&Ps[wid][fr * 72 + fq * 8 + 32];

      // O += V^T · P
      __builtin_amdgcn_s_setprio(1);
#pragma unroll
      for (int kk = 0; kk < 2; ++kk)
#pragma unroll
        for (int nt = 0; nt < 4; ++nt) {
          int r = nt * 16 + fr;
          int cb = fq * 16 + kk * 64;
          bf16x8 vf = *(const bf16x8*)((const char*)Vs[cur] + (((r << 7) + cb) ^ ((r & 7) << 4)));
          o_acc[nt] = MFMA16(vf, kk == 0 ? pf0 : pf1, o_acc[nt]);
        }
      __builtin_amdgcn_s_setprio(0);

      // -------- split-barrier counted-vmcnt tail --------
      if (kt + 2 < NT) {
        __builtin_amdgcn_sched_barrier(0);
        __builtin_amdgcn_s_barrier();       // (1) all waves done with buf[cur]
        __builtin_amdgcn_sched_barrier(0);
        stage(cur, kt + 2, q0);             // overwrite just-freed buffer
      }
      if (kt + 1 < NT) {
        if (kt + 2 < NT) asm volatile("s_waitcnt vmcnt(8)" ::: "memory");
        else             asm volatile("s_waitcnt vmcnt(0)" ::: "memory");
        __builtin_amdgcn_sched_barrier(0);
        __builtin_amdgcn_s_barrier();       // (2) tile kt+1 landed
        __builtin_amdgcn_sched_barrier(0);
      }
      cur ^= 1;
    }

    // normalize + write merged-head bf16 [4096][1024] for this half
    float rl = 1.0f / l_run;
    size_t row = (size_t)(b * 1024 + q0 + wid * 16 + fr);
#pragma unroll
    for (int nt = 0; nt < 4; ++nt) {
      uint2 sv;
      sv.x = cvt_pk_bf16(o_acc[nt][0] * rl, o_acc[nt][1] * rl);
      sv.y = cvt_pk_bf16(o_acc[nt][2] * rl, o_acc[nt][3] * rl);
      int col = (h & 15) * 64 + nt * 16 + fq * 4;
      *(uint2*)&Aout[row * 1024 + col] = sv;
    }
  }
}

// ---------------------------------------------------------------------------
extern "C" void kernel_launch(void* const* d_in, const int* in_sizes, int n_in,
                              void* d_out, int out_size, void* d_ws, size_t ws_size,
                              hipStream_t stream) {
  const float* query = (const float*)d_in[0];
  const float* key   = (const float*)d_in[1];
  const float* value = (const float*)d_in[2];
  const float* mask  = (const float*)d_in[3];
  const float* wts   = (const float*)d_in[4];
  const float* Wq    = (const float*)d_in[5];
  const float* bq    = (const float*)d_in[6];
  const float* Wk    = (const float*)d_in[7];
  const float* bk    = (const float*)d_in[8];
  const float* Wv    = (const float*)d_in[9];
  const float* bv    = (const float*)d_in[10];
  const float* Wo    = (const float*)d_in[11];
  const float* bo    = (const float*)d_in[12];

  char* ws = (char*)d_ws;
  const size_t MB = 1u << 20;
  short* qbf = (short*)(ws + 0);        // 8 MB  (reused as attn out)
  short* kbf = (short*)(ws + 8 * MB);   // 8 MB
  short* vbf = (short*)(ws + 16 * MB);  // 8 MB
  short* Wqb = (short*)(ws + 24 * MB);  // 2 MB
  short* Wkb = (short*)(ws + 26 * MB);
  short* Wvb = (short*)(ws + 28 * MB);
  short* Wob = (short*)(ws + 30 * MB);
  short* Qh  = (short*)(ws + 32 * MB);  // 8 MB [B,N,T,DH]
  short* Kh  = (short*)(ws + 40 * MB);  // 8 MB [B,N,T,DH]
  short* Vth = (short*)(ws + 48 * MB);  // 8 MB [B,N,DH,T]
  short* attnb = qbf;                   // alias: qbf dead after proj_qkv

  cvt_all<<<dim3(2048), dim3(256), 0, stream>>>(query, key, value, Wq, Wk, Wv, Wo,
                                                qbf, kbf, vbf, Wqb, Wkb, Wvb, Wob);
  proj_qkv<<<dim3(32, 8, 3), dim3(256), 0, stream>>>(qbf, kbf, vbf, Wqb, Wkb, Wvb,
                                                     bq, bk, bv, Qh, Kh, Vth);
  attn_kernel<<<dim3(8, 64), dim3(256), 0, stream>>>(Qh, Kh, Vth, wts, mask, attnb);
  gemm_out<<<dim3(32, 8), dim3(512), 0, stream>>>(attnb, Wob, bo, (float*)d_out);
}